// Round 7
// baseline (262.144 us; speedup 1.0000x reference)
//
#include <hip/hip_runtime.h>

#define NPTS 8192
#define NB 4
#define CH 64
#define KNN 16
#define CAP2 128          // epilogue rank slots (2 per lane; total expected ~25-40)
#define SEGC 64           // per-wave survivor segment (quarter expected ~6-10; P(>64)~0)
#define SLACK 4e-3f       // > 2*eps of bf16 hi/lo MFMA distance approx (eps ~ 5e-4)
#define MNVP 129          // s_minv pad: 129 % 32 = 1 -> conflict-free column reads

using bf16x8 = __attribute__((ext_vector_type(8))) __bf16;
using us8    = __attribute__((ext_vector_type(8))) unsigned short;
using f32x4  = __attribute__((ext_vector_type(4))) float;
using f32x16 = __attribute__((ext_vector_type(16))) float;

__device__ __forceinline__ float bf2f(unsigned short u) {
    return __uint_as_float(((unsigned)u) << 16);
}
__device__ __forceinline__ unsigned short f2bf(float f) {
    unsigned u = __float_as_uint(f);
    u += 0x7fffu + ((u >> 16) & 1u);
    return (unsigned short)(u >> 16);
}

// split 8 f32 into hi/lo bf16: x = hi + lo. Native casts -> v_cvt_pk_bf16_f32 (RNE,
// bit-identical to the manual round-to-nearest-even f2bf) at ~1/2 the VALU ops.
__device__ __forceinline__ void split8(const float* x, bf16x8& hi, bf16x8& lo) {
#pragma unroll
    for (int j = 0; j < 8; ++j) {
        const __bf16 h = (__bf16)x[j];
        hi[j] = h;
        lo[j] = (__bf16)(x[j] - (float)h);
    }
}

// in-wave LDS fence: order prior LDS writes before subsequent reads, no cross-wave stall
__device__ __forceinline__ void wave_fence() {
    asm volatile("s_waitcnt lgkmcnt(0)" ::: "memory");
    __builtin_amdgcn_wave_barrier();
}

// lexicographic (d,i) compare: true if (dB,iB) < (dA,iA)
__device__ __forceinline__ bool lex_lt(float dB, int iB, float dA, int iA) {
    return (dB < dA) || ((dB == dA) && (iB < iA));
}

// ---------------- Kernel 0: pack {x,y,z,sq} + 32x32x16 MFMA B-fragments --------------
// (frozen, passed rounds 3/5/6)
__global__ __launch_bounds__(256) void pack_kernel(const float* __restrict__ pts,
                                                   float4* __restrict__ pts4,
                                                   uint4* __restrict__ bfrag) {
    const int i = blockIdx.x * 256 + threadIdx.x;   // 0..32767
    const float x = pts[i * 3 + 0];
    const float y = pts[i * 3 + 1];
    const float z = pts[i * 3 + 2];
    const float sq = (x * x + y * y) + z * z;       // reference-path formula
    pts4[i] = make_float4(x, y, z, sq);

    const float sx = -2.f * x, sy = -2.f * y, sz = -2.f * z;
    const unsigned short shx = f2bf(sx), shy = f2bf(sy), shz = f2bf(sz);
    const unsigned short slx = f2bf(sx - bf2f(shx));
    const unsigned short sly = f2bf(sy - bf2f(shy));
    const unsigned short slz = f2bf(sz - bf2f(shz));
    const unsigned short sqh = f2bf(sq), sql = f2bf(sq - bf2f(sqh));

    const int b = i >> 13, n = i & (NPTS - 1);
    const int tile = n >> 5, col = n & 31;
    uint4* base = bfrag + ((size_t)(b * 256 + tile)) * 64;

    unsigned short g0[8], g1[8];
    g0[0] = shx; g0[1] = shy; g0[2] = shz; g0[3] = slx;
    g0[4] = sly; g0[5] = slz; g0[6] = shx; g0[7] = shy;   // k0..7
    g1[0] = shz; g1[1] = slx; g1[2] = sly; g1[3] = slz;
    g1[4] = sqh; g1[5] = sql; g1[6] = 0;   g1[7] = 0;     // k8..15
    base[col]      = *(const uint4*)g0;
    base[32 + col] = *(const uint4*)g1;
}

// A-fragment for one query point, k-half kh = lane>>5 (proven k-plan)
__device__ __forceinline__ bf16x8 make_afrag(const float4 qp, const int kh) {
    const unsigned short hx = f2bf(qp.x), hy = f2bf(qp.y), hz = f2bf(qp.z);
    const unsigned short lx = f2bf(qp.x - bf2f(hx));
    const unsigned short ly = f2bf(qp.y - bf2f(hy));
    const unsigned short lz = f2bf(qp.z - bf2f(hz));
    us8 u;
#pragma unroll
    for (int j = 0; j < 8; ++j) u[j] = 0;
    if (kh == 0) {
        u[0] = hx; u[1] = hy; u[2] = hz; u[3] = hx;
        u[4] = hy; u[5] = hz; u[6] = lx; u[7] = ly;       // k0..7
    } else {
        u[0] = lz; u[1] = lx; u[2] = ly; u[3] = lz;
        u[4] = 0x3f80u; u[5] = 0x3f80u;                   // 1.0 * sq_hi/lo, k8..15
    }
    return __builtin_bit_cast(bf16x8, u);
}

// ---------------- Kernel 1: MFMA KNN (32x32x16, candidate-quartered waves) -----------
// Block = 4 waves = 32 queries; wave w covers tiles [w*64, w*64+64). Grid 1024.
// Pass A: stream minima (128 streams/query -> 64); U = rank-15 of 64. Pass B: ballot
// compaction into WAVE-PRIVATE survivor segments (no LDS atomics, no ds_add_rtn
// latency chains -- round-6 PMC showed those were ~60% of the stall). Epilogue: exact
// f32 distances + lex-(d,idx) rank over the segment union (identical semantics).
__global__ __launch_bounds__(256, 4) void knn_mfma_kernel(const float4* __restrict__ pts4,
                                                          const uint4* __restrict__ bfrag,
                                                          int* __restrict__ idx_out) {
    __shared__ alignas(16) char s_union[32 * SEGC * 4 * 4];   // 32 KB
    float (*s_minv)[MNVP]     = (float(*)[MNVP])s_union;      // [32][129], dead after B3
    int   (*s_surv)[4 * SEGC] = (int(*)[4 * SEGC])s_union;    // [32][256], written after B3
    __shared__ float s_U[32];
    __shared__ int   s_cntw[4][32];                           // per-wave survivor counts
    __shared__ float s_rd[4][CAP2];
    __shared__ int   s_ri[4][CAP2];

    const int tid  = threadIdx.x;
    const int w    = tid >> 6, lane = tid & 63;
    const int col  = lane & 31, hi = lane >> 5;
    const int qbase = blockIdx.x * 32;               // global query id (= b*8192 + n0)
    const int b = qbase >> 13, n0 = qbase & (NPTS - 1);
    const float4* pb = pts4 + (size_t)b * NPTS;

    // A-fragment: rows = queries n0..n0+31
    const bf16x8 af = make_afrag(pb[n0 + col], hi);

    const int wtile = w * 64;
    const uint4* bpb = bfrag + ((size_t)b * 256) * 64;    // batch base
    const f32x16 zero16 = {0.f, 0.f, 0.f, 0.f, 0.f, 0.f, 0.f, 0.f,
                           0.f, 0.f, 0.f, 0.f, 0.f, 0.f, 0.f, 0.f};

    // ---- Pass A: stream minima of e = |c|^2 - 2 q.c, 8-deep prefetch ring ----
    float m0[16];
#pragma unroll
    for (int r = 0; r < 16; ++r) m0[r] = 3.4e38f;

    uint4 pf0 = bpb[(wtile + 0) * 64 + lane], pf1 = bpb[(wtile + 1) * 64 + lane];
    uint4 pf2 = bpb[(wtile + 2) * 64 + lane], pf3 = bpb[(wtile + 3) * 64 + lane];
    uint4 pf4 = bpb[(wtile + 4) * 64 + lane], pf5 = bpb[(wtile + 5) * 64 + lane];
    uint4 pf6 = bpb[(wtile + 6) * 64 + lane], pf7 = bpb[(wtile + 7) * 64 + lane];

#define STEP_A(PF, KOFF)                                                              \
    {                                                                                 \
        const bf16x8 bw = __builtin_bit_cast(bf16x8, PF);                             \
        PF = bpb[min(wtile + tb + 8 + KOFF, 255) * 64 + lane];                        \
        const f32x16 a0 = __builtin_amdgcn_mfma_f32_32x32x16_bf16(af, bw, zero16, 0, 0, 0); \
        _Pragma("unroll")                                                             \
        for (int r = 0; r < 16; ++r) m0[r] = fminf(m0[r], a0[r]);                     \
    }

    for (int tt = 0; tt < 8; ++tt) {
        const int tb = tt * 8;
        STEP_A(pf0, 0)
        STEP_A(pf1, 1)
        STEP_A(pf2, 2)
        STEP_A(pf3, 3)
        STEP_A(pf4, 4)
        STEP_A(pf5, 5)
        STEP_A(pf6, 6)
        STEP_A(pf7, 7)
    }
#undef STEP_A

    // C/D layout (verified): col=lane&31 (cand-class), row=(r&3)+8*(r>>2)+4*hi (query).
#pragma unroll
    for (int r = 0; r < 16; ++r) {
        const int q0 = (r & 3) + 8 * (r >> 2) + 4 * hi;
        s_minv[q0][w * 32 + col] = m0[r];
    }
    __syncthreads();                                  // B1 (all 128 streams written)

    // ---- combine 128 -> 64 streams (pairwise min over disjoint candidate sets) ----
    for (int e = tid; e < 32 * 64; e += 256) {
        const int q = e >> 6, j = e & 63;
        s_minv[q][j] = fminf(s_minv[q][j], s_minv[q][64 + j]);
    }
    __syncthreads();                                  // B2

    // ---- U select: rank-15 (16th smallest) of 64 stream minima per query ----
    for (int qi = 0; qi < 8; ++qi) {
        const int q = w * 8 + qi;
        const float v = s_minv[q][lane];
        int rk = 0;
#pragma unroll 8
        for (int j = 0; j < 64; ++j) {
            const float vv = s_minv[q][j];
            rk += ((vv < v) || (vv == v && j < lane)) ? 1 : 0;
        }
        if (rk == 15) s_U[q] = v;                     // exactly one (value,stream) wins
    }
    __syncthreads();                                  // B3 (last s_minv read; s_surv writable)

    // ---- Pass B: ballot compaction into wave-private segments (atomic-free) ----
    float U0[16];
#pragma unroll
    for (int r = 0; r < 16; ++r) {
        const int q0 = (r & 3) + 8 * (r >> 2) + 4 * hi;
        U0[r] = s_U[q0] + SLACK;
    }
    int cnt[32];                                      // wave-uniform scalar counters
#pragma unroll
    for (int q = 0; q < 32; ++q) cnt[q] = 0;

    pf0 = bpb[(wtile + 0) * 64 + lane]; pf1 = bpb[(wtile + 1) * 64 + lane];
    pf2 = bpb[(wtile + 2) * 64 + lane]; pf3 = bpb[(wtile + 3) * 64 + lane];
    pf4 = bpb[(wtile + 4) * 64 + lane]; pf5 = bpb[(wtile + 5) * 64 + lane];
    pf6 = bpb[(wtile + 6) * 64 + lane]; pf7 = bpb[(wtile + 7) * 64 + lane];

#define STEP_B(PF, KOFF)                                                              \
    {                                                                                 \
        const bf16x8 bw = __builtin_bit_cast(bf16x8, PF);                             \
        PF = bpb[min(wtile + tb + 8 + KOFF, 255) * 64 + lane];                        \
        const f32x16 a0 = __builtin_amdgcn_mfma_f32_32x32x16_bf16(af, bw, zero16, 0, 0, 0); \
        const int cand = (wtile + tb + KOFF) * 32 + col;                              \
        _Pragma("unroll")                                                             \
        for (int r = 0; r < 16; ++r) {                                                \
            const int QA = (r & 3) + 8 * (r >> 2);    /* compile-time per r */        \
            const bool cc = a0[r] <= U0[r];                                           \
            const unsigned long long mm = __ballot(cc);                               \
            const unsigned mlo = (unsigned)mm;                                        \
            const unsigned mhi = (unsigned)(mm >> 32);                                \
            if (mlo) {                                /* uniform branch, ~82% skip */ \
                if (cc && hi == 0) {                                                  \
                    const int pos = cnt[QA] + __popc(mlo & ((1u << col) - 1u));       \
                    if (pos < SEGC) s_surv[QA][w * SEGC + pos] = cand;                \
                }                                                                     \
                cnt[QA] += __popc(mlo);                                               \
            }                                                                         \
            if (mhi) {                                                                \
                if (cc && hi == 1) {                                                  \
                    const int pos = cnt[QA + 4] + __popc(mhi & ((1u << col) - 1u));   \
                    if (pos < SEGC) s_surv[QA + 4][w * SEGC + pos] = cand;            \
                }                                                                     \
                cnt[QA + 4] += __popc(mhi);                                           \
            }                                                                         \
        }                                                                             \
    }

    for (int tt = 0; tt < 8; ++tt) {
        const int tb = tt * 8;
        STEP_B(pf0, 0)
        STEP_B(pf1, 1)
        STEP_B(pf2, 2)
        STEP_B(pf3, 3)
        STEP_B(pf4, 4)
        STEP_B(pf5, 5)
        STEP_B(pf6, 6)
        STEP_B(pf7, 7)
    }
#undef STEP_B

    // publish per-wave counts: build per-lane value via select chain (static idx only)
    {
        int myc = 0;
#pragma unroll
        for (int q = 0; q < 32; ++q) myc = (col == q) ? cnt[q] : myc;
        if (lane < 32) s_cntw[w][col] = myc;
    }
    __syncthreads();                                  // B4

    // ---- Epilogue: exact distances + lex rank over segment union (same semantics) --
    for (int qi = 0; qi < 8; ++qi) {
        const int q = w * 8 + qi;
        const int c0 = min(s_cntw[0][q], SEGC), c1 = min(s_cntw[1][q], SEGC);
        const int c2 = min(s_cntw[2][q], SEGC), c3 = min(s_cntw[3][q], SEGC);
        const int b1 = c0, b2 = c0 + c1, b3 = c0 + c1 + c2;
        const int n = min(b3 + c3, CAP2);             // rank slots: 2 per lane (<=128)
        const float4 qp = pb[n0 + q];
        float d1 = 3.4e38f, d2 = 3.4e38f;
        int i1 = -1, i2 = -1;
        if (lane < n) {
            const int seg = (lane >= b1) + (lane >= b2) + (lane >= b3);
            const int off = seg == 0 ? 0 : (seg == 1 ? b1 : (seg == 2 ? b2 : b3));
            i1 = s_surv[q][seg * SEGC + (lane - off)];
            const float4 v = pb[i1];
            float dot = qp.x * v.x;
            dot = fmaf(qp.y, v.y, dot);
            dot = fmaf(qp.z, v.z, dot);
            d1 = fmaf(dot, -2.0f, qp.w + v.w);        // identical rounding to reference path
        }
        const int l2 = 64 + lane;
        if (l2 < n) {
            const int seg = (l2 >= b1) + (l2 >= b2) + (l2 >= b3);
            const int off = seg == 0 ? 0 : (seg == 1 ? b1 : (seg == 2 ? b2 : b3));
            i2 = s_surv[q][seg * SEGC + (l2 - off)];
            const float4 v = pb[i2];
            float dot = qp.x * v.x;
            dot = fmaf(qp.y, v.y, dot);
            dot = fmaf(qp.z, v.z, dot);
            d2 = fmaf(dot, -2.0f, qp.w + v.w);
        }
        s_rd[w][lane] = d1;      s_ri[w][lane] = i1;
        s_rd[w][64 + lane] = d2; s_ri[w][64 + lane] = i2;
        wave_fence();                                 // in-wave LDS producer/consumer
        int r1 = 0, r2 = 0;
        int k = 0;
        for (; k + 3 < n; k += 4) {
            const float dk0 = s_rd[w][k + 0], dk1 = s_rd[w][k + 1];
            const float dk2 = s_rd[w][k + 2], dk3 = s_rd[w][k + 3];
            const int   ik0 = s_ri[w][k + 0], ik1 = s_ri[w][k + 1];
            const int   ik2 = s_ri[w][k + 2], ik3 = s_ri[w][k + 3];
            r1 += (lex_lt(dk0, ik0, d1, i1) ? 1 : 0) + (lex_lt(dk1, ik1, d1, i1) ? 1 : 0)
                + (lex_lt(dk2, ik2, d1, i1) ? 1 : 0) + (lex_lt(dk3, ik3, d1, i1) ? 1 : 0);
            r2 += (lex_lt(dk0, ik0, d2, i2) ? 1 : 0) + (lex_lt(dk1, ik1, d2, i2) ? 1 : 0)
                + (lex_lt(dk2, ik2, d2, i2) ? 1 : 0) + (lex_lt(dk3, ik3, d2, i2) ? 1 : 0);
        }
        for (; k < n; ++k) {
            const float dk = s_rd[w][k];
            const int   ik = s_ri[w][k];
            r1 += lex_lt(dk, ik, d1, i1) ? 1 : 0;
            r2 += lex_lt(dk, ik, d2, i2) ? 1 : 0;
        }
        if (lane < n && r1 < KNN) idx_out[(size_t)(qbase + q) * KNN + r1] = i1;
        if (l2 < n && r2 < KNN)   idx_out[(size_t)(qbase + q) * KNN + r2] = i2;
        wave_fence();                                 // scratch WAR across queries (in-wave)
    }
}

// ---------------- Kernel 2: MFMA agg — wave-decoupled (frozen, passed round 6) -------
#define MIDP 132   // s_mid leading-dim pad: 128 -> 132 breaks bank-aligned row stride
__global__ __launch_bounds__(256) void agg_kernel(
    const float* __restrict__ pts,
    const float* __restrict__ feat,
    const float* __restrict__ w_geom,
    const float* __restrict__ g1, const float* __restrict__ b1,
    const float* __restrict__ m1, const float* __restrict__ v1,
    const float* __restrict__ w_sem,
    const float* __restrict__ g2, const float* __restrict__ b2,
    const float* __restrict__ m2, const float* __restrict__ v2,
    const float* __restrict__ w_fuse,
    const float* __restrict__ g3, const float* __restrict__ b3,
    const float* __restrict__ m3, const float* __restrict__ v3,
    const int* __restrict__ knn_idx,
    float* __restrict__ outp) {

    __shared__ alignas(16) unsigned short s_wsemB[8192];    // 16 frags x 64 lanes x 8 bf16
    __shared__ alignas(16) unsigned short s_wfuseB[8192];
    __shared__ float s_wg[6][64];
    __shared__ float s_s1[64], s_b1[64], s_s2[64], s_b2[64], s_s3[64], s_b3[64];
    __shared__ alignas(16) float s_mid[4][16][MIDP];
    __shared__ float s_pm[4][4][64];
    __shared__ float s_gd[4][16][4];

    const int tid = threadIdx.x;
    const int w = tid >> 6, lane = tid & 63;
    const int r = lane & 15, qd = lane >> 4;

    for (int e = tid; e < 1024; e += 256) {          // e = (kc*4+n0)*64 + ln
        const int ln = e & 63;
        const int o = ((e >> 6) & 3) * 16 + (ln & 15);
        const int c = (e >> 8) * 32 + (ln >> 4) * 8;
        unsigned short ts[8], tf[8];
#pragma unroll
        for (int j = 0; j < 8; ++j) {
            ts[j] = f2bf(w_sem [o * 128 + c + j]);
            tf[j] = f2bf(w_fuse[o * 128 + c + j]);
        }
        *(uint4*)&s_wsemB [e * 8] = *(uint4*)ts;
        *(uint4*)&s_wfuseB[e * 8] = *(uint4*)tf;
    }
    for (int e = tid; e < 384; e += 256) {
        const int c = e >> 6, o = e & 63;
        s_wg[c][o] = w_geom[o * 6 + c];
    }
    if (tid < 64) {
        float s;
        s = g1[tid] / sqrtf(v1[tid] + 1e-5f);
        s_s1[tid] = s; s_b1[tid] = b1[tid] - m1[tid] * s;
        s = g2[tid] / sqrtf(v2[tid] + 1e-5f);
        s_s2[tid] = s; s_b2[tid] = b2[tid] - m2[tid] * s;
        s = g3[tid] / sqrtf(v3[tid] + 1e-5f);
        s_s3[tid] = s; s_b3[tid] = b3[tid] - m3[tid] * s;
    }
    __syncthreads();   // ONLY global barrier: weight staging

    const f32x4 zero = {0.f, 0.f, 0.f, 0.f};

    const int pv0 = blockIdx.x * 16 + w * 4;
    // prefetch point 0's index + center coords
    int nidx_nx;
    float cpx_nx, cpy_nx, cpz_nx;
    {
        const int b = pv0 >> 13, n = pv0 & (NPTS - 1);
        const long pbase = (long)b * NPTS + n;
        nidx_nx = knn_idx[pbase * KNN + r];
        cpx_nx = pts[pbase * 3 + 0];
        cpy_nx = pts[pbase * 3 + 1];
        cpz_nx = pts[pbase * 3 + 2];
    }

#pragma unroll
    for (int i = 0; i < 4; ++i) {
        const int pv = pv0 + i;
        const int b = pv >> 13, n = pv & (NPTS - 1);
        const long pbase = (long)b * NPTS + n;
        const int   nidx_r = nidx_nx;                 // this lane's MFMA-row neighbor
        const float cpx = cpx_nx, cpy = cpy_nx, cpz = cpz_nx;
        const long  nb = (long)b * NPTS + nidx_r;

        if (lane < 16) {                              // r == lane here
            s_gd[w][lane][0] = pts[nb * 3 + 0] - cpx;
            s_gd[w][lane][1] = pts[nb * 3 + 1] - cpy;
            s_gd[w][lane][2] = pts[nb * 3 + 2] - cpz;
        }

        // A-fragments: center features + (neighbor - center), direct global loads
        bf16x8 ah[4], al[4];
        {
            const float* cf = feat + pbase * CH;
            const float* fp = feat + nb * CH;
            float xs[8];
#pragma unroll
            for (int kc = 0; kc < 2; ++kc) {
                const int base = kc * 32 + qd * 8;
                const float4 c0 = *(const float4*)(cf + base);
                const float4 c1 = *(const float4*)(cf + base + 4);
                const float4 v0 = *(const float4*)(fp + base);
                const float4 v1 = *(const float4*)(fp + base + 4);
                xs[0] = c0.x; xs[1] = c0.y; xs[2] = c0.z; xs[3] = c0.w;
                xs[4] = c1.x; xs[5] = c1.y; xs[6] = c1.z; xs[7] = c1.w;
                split8(xs, ah[kc], al[kc]);
                xs[0] = v0.x - c0.x; xs[1] = v0.y - c0.y;
                xs[2] = v0.z - c0.z; xs[3] = v0.w - c0.w;
                xs[4] = v1.x - c1.x; xs[5] = v1.y - c1.y;
                xs[6] = v1.z - c1.z; xs[7] = v1.w - c1.w;
                split8(xs, ah[2 + kc], al[2 + kc]);
            }
        }
        f32x4 acc[4] = {zero, zero, zero, zero};
#pragma unroll
        for (int kc = 0; kc < 4; ++kc) {
#pragma unroll
            for (int n0 = 0; n0 < 4; ++n0) {
                const bf16x8 bw = *(const bf16x8*)&s_wsemB[((kc * 4 + n0) * 64 + lane) * 8];
                acc[n0] = __builtin_amdgcn_mfma_f32_16x16x32_bf16(ah[kc], bw, acc[n0], 0, 0, 0);
                acc[n0] = __builtin_amdgcn_mfma_f32_16x16x32_bf16(al[kc], bw, acc[n0], 0, 0, 0);
            }
        }
#pragma unroll
        for (int n0 = 0; n0 < 4; ++n0) {
            const int nn = n0 * 16 + r;
            const float sv = s_s2[nn], bv = s_b2[nn];
#pragma unroll
            for (int reg = 0; reg < 4; ++reg) {
                s_mid[w][qd * 4 + reg][64 + nn] = fmaxf(fmaf(acc[n0][reg], sv, bv), 0.f);
            }
        }

        // prefetch next point's idx + center coords (overlaps geom/fuse below)
        if (i < 3) {
            const int pvn = pv + 1;
            const int bn = pvn >> 13, nn2 = pvn & (NPTS - 1);
            const long pbn = (long)bn * NPTS + nn2;
            nidx_nx = knn_idx[pbn * KNN + r];
            cpx_nx = pts[pbn * 3 + 0];
            cpy_nx = pts[pbn * 3 + 1];
            cpz_nx = pts[pbn * 3 + 2];
        }

        wave_fence();                                 // F1: s_gd (and sem-mid) visible

        {
            const int o = lane;
            float cg = cpx * s_wg[0][o];
            cg = fmaf(cpy, s_wg[1][o], cg);
            cg = fmaf(cpz, s_wg[2][o], cg);
            const float s1o = s_s1[o], b1o = s_b1[o];
#pragma unroll
            for (int r2 = 0; r2 < 16; ++r2) {
                float g = cg;
                g = fmaf(s_gd[w][r2][0], s_wg[3][o], g);
                g = fmaf(s_gd[w][r2][1], s_wg[4][o], g);
                g = fmaf(s_gd[w][r2][2], s_wg[5][o], g);
                s_mid[w][r2][o] = fmaxf(fmaf(g, s1o, b1o), 0.f);
            }
        }
        wave_fence();                                 // F2: mid complete (geom+sem)

        bf16x8 fh[4], fl[4];
        {
            float xs[8];
#pragma unroll
            for (int kc = 0; kc < 4; ++kc) {
                const float* mp = &s_mid[w][r][kc * 32 + qd * 8];
#pragma unroll
                for (int j = 0; j < 8; ++j) xs[j] = mp[j];
                split8(xs, fh[kc], fl[kc]);
            }
        }
        f32x4 acc2[4] = {zero, zero, zero, zero};
#pragma unroll
        for (int kc = 0; kc < 4; ++kc) {
#pragma unroll
            for (int n0 = 0; n0 < 4; ++n0) {
                const bf16x8 bw = *(const bf16x8*)&s_wfuseB[((kc * 4 + n0) * 64 + lane) * 8];
                acc2[n0] = __builtin_amdgcn_mfma_f32_16x16x32_bf16(fh[kc], bw, acc2[n0], 0, 0, 0);
                acc2[n0] = __builtin_amdgcn_mfma_f32_16x16x32_bf16(fl[kc], bw, acc2[n0], 0, 0, 0);
            }
        }
#pragma unroll
        for (int n0 = 0; n0 < 4; ++n0) {
            const int nn = n0 * 16 + r;
            const float sv = s_s3[nn], bv = s_b3[nn];
            float mx = 0.f;   // relu outputs >= 0
#pragma unroll
            for (int reg = 0; reg < 4; ++reg)
                mx = fmaxf(mx, fmaxf(fmaf(acc2[n0][reg], sv, bv), 0.f));
            s_pm[w][qd][nn] = mx;
        }
        wave_fence();                                 // F3: pm visible
        {
            const int o = lane;
            const float rv = fmaxf(fmaxf(s_pm[w][0][o], s_pm[w][1][o]),
                                   fmaxf(s_pm[w][2][o], s_pm[w][3][o]));
            outp[pbase * CH + o] = rv;
        }
        wave_fence();                                 // F4: WAR before next iter reuse
    }
}

extern "C" void kernel_launch(void* const* d_in, const int* in_sizes, int n_in,
                              void* d_out, int out_size, void* d_ws, size_t ws_size,
                              hipStream_t stream) {
    (void)in_sizes; (void)n_in; (void)out_size; (void)ws_size;
    const float* pts    = (const float*)d_in[0];
    const float* feat   = (const float*)d_in[1];
    const float* w_geom = (const float*)d_in[2];
    const float* g1     = (const float*)d_in[3];
    const float* b1     = (const float*)d_in[4];
    const float* m1     = (const float*)d_in[5];
    const float* v1     = (const float*)d_in[6];
    const float* w_sem  = (const float*)d_in[7];
    const float* g2     = (const float*)d_in[8];
    const float* b2     = (const float*)d_in[9];
    const float* m2     = (const float*)d_in[10];
    const float* v2     = (const float*)d_in[11];
    const float* w_fuse = (const float*)d_in[12];
    const float* g3     = (const float*)d_in[13];
    const float* b3     = (const float*)d_in[14];
    const float* m3     = (const float*)d_in[15];
    const float* v3     = (const float*)d_in[16];

    int*    idx_final = (int*)d_ws;                             // 2 MB @ 0
    uint4*  bfrag     = (uint4*)((char*)d_ws + (2ull << 20));   // 1 MB @ 2MB
    float4* pts4      = (float4*)((char*)d_ws + (4ull << 20));  // 512 KB @ 4MB

    pack_kernel<<<dim3(NB * NPTS / 256), dim3(256), 0, stream>>>(pts, pts4, bfrag);
    knn_mfma_kernel<<<dim3(NB * NPTS / 32), dim3(256), 0, stream>>>(pts4, bfrag, idx_final);

    agg_kernel<<<dim3(2048), dim3(256), 0, stream>>>(
        pts, feat, w_geom, g1, b1, m1, v1, w_sem, g2, b2, m2, v2,
        w_fuse, g3, b3, m3, v3, idx_final, (float*)d_out);
}

// Round 8
// 248.461 us; speedup vs baseline: 1.0551x; 1.0551x over previous
//
#include <hip/hip_runtime.h>

#define NPTS 8192
#define NB 4
#define CH 64
#define KNN 16
#define CAP2 128          // survivors per query (expected ~20-40; passed rounds at 128)
#define SLACK 4e-3f       // > 2*eps of bf16 hi/lo MFMA distance approx (eps ~ 5e-4)
#define MNVP 129          // s_minv pad: 129 % 32 = 1 -> conflict-free column reads

using bf16x8 = __attribute__((ext_vector_type(8))) __bf16;
using us8    = __attribute__((ext_vector_type(8))) unsigned short;
using f32x4  = __attribute__((ext_vector_type(4))) float;
using f32x16 = __attribute__((ext_vector_type(16))) float;

__device__ __forceinline__ float bf2f(unsigned short u) {
    return __uint_as_float(((unsigned)u) << 16);
}
__device__ __forceinline__ unsigned short f2bf(float f) {
    unsigned u = __float_as_uint(f);
    u += 0x7fffu + ((u >> 16) & 1u);
    return (unsigned short)(u >> 16);
}

// split 8 f32 into hi/lo bf16: x = hi + lo (native casts -> v_cvt_pk_bf16_f32, RNE)
__device__ __forceinline__ void split8(const float* x, bf16x8& hi, bf16x8& lo) {
#pragma unroll
    for (int j = 0; j < 8; ++j) {
        const __bf16 h = (__bf16)x[j];
        hi[j] = h;
        lo[j] = (__bf16)(x[j] - (float)h);
    }
}

// in-wave LDS fence: order prior LDS writes before subsequent reads, no cross-wave stall
__device__ __forceinline__ void wave_fence() {
    asm volatile("s_waitcnt lgkmcnt(0)" ::: "memory");
    __builtin_amdgcn_wave_barrier();
}

// lexicographic (d,i) compare: true if (dB,iB) < (dA,iA)
__device__ __forceinline__ bool lex_lt(float dB, int iB, float dA, int iA) {
    return (dB < dA) || ((dB == dA) && (iB < iA));
}

// ---------------- Kernel 0: pack {x,y,z,sq} + 32x32x16 MFMA B-fragments --------------
// (frozen, passed rounds 3/5/6/7)
__global__ __launch_bounds__(256) void pack_kernel(const float* __restrict__ pts,
                                                   float4* __restrict__ pts4,
                                                   uint4* __restrict__ bfrag) {
    const int i = blockIdx.x * 256 + threadIdx.x;   // 0..32767
    const float x = pts[i * 3 + 0];
    const float y = pts[i * 3 + 1];
    const float z = pts[i * 3 + 2];
    const float sq = (x * x + y * y) + z * z;       // reference-path formula
    pts4[i] = make_float4(x, y, z, sq);

    const float sx = -2.f * x, sy = -2.f * y, sz = -2.f * z;
    const unsigned short shx = f2bf(sx), shy = f2bf(sy), shz = f2bf(sz);
    const unsigned short slx = f2bf(sx - bf2f(shx));
    const unsigned short sly = f2bf(sy - bf2f(shy));
    const unsigned short slz = f2bf(sz - bf2f(shz));
    const unsigned short sqh = f2bf(sq), sql = f2bf(sq - bf2f(sqh));

    const int b = i >> 13, n = i & (NPTS - 1);
    const int tile = n >> 5, col = n & 31;
    uint4* base = bfrag + ((size_t)(b * 256 + tile)) * 64;

    unsigned short g0[8], g1[8];
    g0[0] = shx; g0[1] = shy; g0[2] = shz; g0[3] = slx;
    g0[4] = sly; g0[5] = slz; g0[6] = shx; g0[7] = shy;   // k0..7
    g1[0] = shz; g1[1] = slx; g1[2] = sly; g1[3] = slz;
    g1[4] = sqh; g1[5] = sql; g1[6] = 0;   g1[7] = 0;     // k8..15
    base[col]      = *(const uint4*)g0;
    base[32 + col] = *(const uint4*)g1;
}

// A-fragment for one query point, k-half kh = lane>>5 (proven k-plan)
__device__ __forceinline__ bf16x8 make_afrag(const float4 qp, const int kh) {
    const unsigned short hx = f2bf(qp.x), hy = f2bf(qp.y), hz = f2bf(qp.z);
    const unsigned short lx = f2bf(qp.x - bf2f(hx));
    const unsigned short ly = f2bf(qp.y - bf2f(hy));
    const unsigned short lz = f2bf(qp.z - bf2f(hz));
    us8 u;
#pragma unroll
    for (int j = 0; j < 8; ++j) u[j] = 0;
    if (kh == 0) {
        u[0] = hx; u[1] = hy; u[2] = hz; u[3] = hx;
        u[4] = hy; u[5] = hz; u[6] = lx; u[7] = ly;       // k0..7
    } else {
        u[0] = lz; u[1] = lx; u[2] = ly; u[3] = lz;
        u[4] = 0x3f80u; u[5] = 0x3f80u;                   // 1.0 * sq_hi/lo, k8..15
    }
    return __builtin_bit_cast(bf16x8, u);
}

// ---------------- Kernel 1: MFMA KNN — ATOMIC Pass B (round-5 form, measured 93.4 µs).
// Round-7's ballot variant regressed (111 µs): unconditional per-r ballot+branch
// overhead exceeded the rare predicated-atomic cost. Reverted verbatim.
__global__ __launch_bounds__(256, 4) void knn_mfma_kernel(const float4* __restrict__ pts4,
                                                          const uint4* __restrict__ bfrag,
                                                          int* __restrict__ idx_out) {
    __shared__ alignas(16) char s_union[32 * MNVP * 4];   // 16,512 B
    float (*s_minv)[MNVP] = (float(*)[MNVP])s_union;      // [32][129], dead after B3
    int   (*s_surv)[CAP2] = (int(*)[CAP2])s_union;        // [32][128], written after B3
    __shared__ float s_U[32];
    __shared__ int   s_cnt[32];
    __shared__ float s_rd[4][CAP2];
    __shared__ int   s_ri[4][CAP2];

    const int tid  = threadIdx.x;
    const int w    = tid >> 6, lane = tid & 63;
    const int col  = lane & 31, hi = lane >> 5;
    const int qbase = blockIdx.x * 32;               // global query id (= b*8192 + n0)
    const int b = qbase >> 13, n0 = qbase & (NPTS - 1);
    const float4* pb = pts4 + (size_t)b * NPTS;

    // A-fragment: rows = queries n0..n0+31
    const bf16x8 af = make_afrag(pb[n0 + col], hi);

    const int wtile = w * 64;
    const uint4* bpb = bfrag + ((size_t)b * 256) * 64;    // batch base
    const f32x16 zero16 = {0.f, 0.f, 0.f, 0.f, 0.f, 0.f, 0.f, 0.f,
                           0.f, 0.f, 0.f, 0.f, 0.f, 0.f, 0.f, 0.f};

    // ---- Pass A: stream minima of e = |c|^2 - 2 q.c, 8-deep prefetch ring ----
    float m0[16];
#pragma unroll
    for (int r = 0; r < 16; ++r) m0[r] = 3.4e38f;

    uint4 pf0 = bpb[(wtile + 0) * 64 + lane], pf1 = bpb[(wtile + 1) * 64 + lane];
    uint4 pf2 = bpb[(wtile + 2) * 64 + lane], pf3 = bpb[(wtile + 3) * 64 + lane];
    uint4 pf4 = bpb[(wtile + 4) * 64 + lane], pf5 = bpb[(wtile + 5) * 64 + lane];
    uint4 pf6 = bpb[(wtile + 6) * 64 + lane], pf7 = bpb[(wtile + 7) * 64 + lane];

#define STEP_A(PF, KOFF)                                                              \
    {                                                                                 \
        const bf16x8 bw = __builtin_bit_cast(bf16x8, PF);                             \
        PF = bpb[min(wtile + tb + 8 + KOFF, 255) * 64 + lane];                        \
        const f32x16 a0 = __builtin_amdgcn_mfma_f32_32x32x16_bf16(af, bw, zero16, 0, 0, 0); \
        _Pragma("unroll")                                                             \
        for (int r = 0; r < 16; ++r) m0[r] = fminf(m0[r], a0[r]);                     \
    }

    for (int tt = 0; tt < 8; ++tt) {
        const int tb = tt * 8;
        STEP_A(pf0, 0)
        STEP_A(pf1, 1)
        STEP_A(pf2, 2)
        STEP_A(pf3, 3)
        STEP_A(pf4, 4)
        STEP_A(pf5, 5)
        STEP_A(pf6, 6)
        STEP_A(pf7, 7)
    }
#undef STEP_A

    // C/D layout (verified): col=lane&31 (cand-class), row=(r&3)+8*(r>>2)+4*hi (query).
#pragma unroll
    for (int r = 0; r < 16; ++r) {
        const int q0 = (r & 3) + 8 * (r >> 2) + 4 * hi;
        s_minv[q0][w * 32 + col] = m0[r];
    }
    if (tid < 32) s_cnt[tid] = 0;
    __syncthreads();                                  // B1 (all 128 streams written)

    // ---- combine 128 -> 64 streams (pairwise min over disjoint candidate sets) ----
    for (int e = tid; e < 32 * 64; e += 256) {
        const int q = e >> 6, j = e & 63;
        s_minv[q][j] = fminf(s_minv[q][j], s_minv[q][64 + j]);
    }
    __syncthreads();                                  // B2

    // ---- U select: rank-15 (16th smallest) of 64 stream minima per query ----
    for (int qi = 0; qi < 8; ++qi) {
        const int q = w * 8 + qi;
        const float v = s_minv[q][lane];
        int rk = 0;
#pragma unroll 8
        for (int j = 0; j < 64; ++j) {
            const float vv = s_minv[q][j];
            rk += ((vv < v) || (vv == v && j < lane)) ? 1 : 0;
        }
        if (rk == 15) s_U[q] = v;                     // exactly one (value,stream) wins
    }
    __syncthreads();                                  // B3 (last s_minv read; s_surv writable)

    // ---- Pass B: gated admission (predicated LDS atomics; rare per lane) ----
    float U0[16];
#pragma unroll
    for (int r = 0; r < 16; ++r) {
        const int q0 = (r & 3) + 8 * (r >> 2) + 4 * hi;
        U0[r] = s_U[q0] + SLACK;
    }

    pf0 = bpb[(wtile + 0) * 64 + lane]; pf1 = bpb[(wtile + 1) * 64 + lane];
    pf2 = bpb[(wtile + 2) * 64 + lane]; pf3 = bpb[(wtile + 3) * 64 + lane];
    pf4 = bpb[(wtile + 4) * 64 + lane]; pf5 = bpb[(wtile + 5) * 64 + lane];
    pf6 = bpb[(wtile + 6) * 64 + lane]; pf7 = bpb[(wtile + 7) * 64 + lane];

#define STEP_B(PF, KOFF)                                                              \
    {                                                                                 \
        const bf16x8 bw = __builtin_bit_cast(bf16x8, PF);                             \
        PF = bpb[min(wtile + tb + 8 + KOFF, 255) * 64 + lane];                        \
        const f32x16 a0 = __builtin_amdgcn_mfma_f32_32x32x16_bf16(af, bw, zero16, 0, 0, 0); \
        const int cand = (wtile + tb + KOFF) * 32 + col;                              \
        _Pragma("unroll")                                                             \
        for (int r = 0; r < 16; ++r) {                                                \
            if (a0[r] <= U0[r]) {                                                     \
                const int q0 = (r & 3) + 8 * (r >> 2) + 4 * hi;                       \
                const int pos = atomicAdd(&s_cnt[q0], 1);                             \
                if (pos < CAP2) s_surv[q0][pos] = cand;                               \
            }                                                                         \
        }                                                                             \
    }

    for (int tt = 0; tt < 8; ++tt) {
        const int tb = tt * 8;
        STEP_B(pf0, 0)
        STEP_B(pf1, 1)
        STEP_B(pf2, 2)
        STEP_B(pf3, 3)
        STEP_B(pf4, 4)
        STEP_B(pf5, 5)
        STEP_B(pf6, 6)
        STEP_B(pf7, 7)
    }
#undef STEP_B
    __syncthreads();                                  // B4

    // ---- Epilogue: exact distances + lex rank (byte-identical semantics) ----
    for (int qi = 0; qi < 8; ++qi) {
        const int q = w * 8 + qi;
        const int n = min(s_cnt[q], CAP2);
        const float4 qp = pb[n0 + q];
        float d1 = 3.4e38f, d2 = 3.4e38f;
        int i1 = -1, i2 = -1;
        if (lane < n) {
            i1 = s_surv[q][lane];
            const float4 v = pb[i1];
            float dot = qp.x * v.x;
            dot = fmaf(qp.y, v.y, dot);
            dot = fmaf(qp.z, v.z, dot);
            d1 = fmaf(dot, -2.0f, qp.w + v.w);        // identical rounding to reference path
        }
        if (64 + lane < n) {
            i2 = s_surv[q][64 + lane];
            const float4 v = pb[i2];
            float dot = qp.x * v.x;
            dot = fmaf(qp.y, v.y, dot);
            dot = fmaf(qp.z, v.z, dot);
            d2 = fmaf(dot, -2.0f, qp.w + v.w);
        }
        s_rd[w][lane] = d1;      s_ri[w][lane] = i1;
        s_rd[w][64 + lane] = d2; s_ri[w][64 + lane] = i2;
        wave_fence();                                 // in-wave LDS producer/consumer
        int r1 = 0, r2 = 0;
        int k = 0;
        for (; k + 3 < n; k += 4) {
            const float dk0 = s_rd[w][k + 0], dk1 = s_rd[w][k + 1];
            const float dk2 = s_rd[w][k + 2], dk3 = s_rd[w][k + 3];
            const int   ik0 = s_ri[w][k + 0], ik1 = s_ri[w][k + 1];
            const int   ik2 = s_ri[w][k + 2], ik3 = s_ri[w][k + 3];
            r1 += (lex_lt(dk0, ik0, d1, i1) ? 1 : 0) + (lex_lt(dk1, ik1, d1, i1) ? 1 : 0)
                + (lex_lt(dk2, ik2, d1, i1) ? 1 : 0) + (lex_lt(dk3, ik3, d1, i1) ? 1 : 0);
            r2 += (lex_lt(dk0, ik0, d2, i2) ? 1 : 0) + (lex_lt(dk1, ik1, d2, i2) ? 1 : 0)
                + (lex_lt(dk2, ik2, d2, i2) ? 1 : 0) + (lex_lt(dk3, ik3, d2, i2) ? 1 : 0);
        }
        for (; k < n; ++k) {
            const float dk = s_rd[w][k];
            const int   ik = s_ri[w][k];
            r1 += lex_lt(dk, ik, d1, i1) ? 1 : 0;
            r2 += lex_lt(dk, ik, d2, i2) ? 1 : 0;
        }
        if (lane < n && r1 < KNN)      idx_out[(size_t)(qbase + q) * KNN + r1] = i1;
        if (64 + lane < n && r2 < KNN) idx_out[(size_t)(qbase + q) * KNN + r2] = i2;
        wave_fence();                                 // scratch WAR across queries (in-wave)
    }
}

// ---------------- Kernel 2: MFMA agg — LDS diet for 3 blocks/CU ----------------------
// Round-5 profile: 74 KB LDS -> 2 blocks/CU (20% occupancy) was the agg limiter.
// (a) s_mid halved to [16][68]: stage sem-mid (ch 64..127 remapped to cols 0..63),
//     read fuse frags kc=2,3, fence, reuse buffer for geom-mid, read kc=0,1. All
//     fragments in registers before the fuse MFMA loop -> accumulation order
//     unchanged -> bit-exact. (b) s_pm replaced by shfl_xor max (associative ->
//     bit-exact). New total ~54.3 KB -> 3 blocks/CU.
#define MIDW 68    // 68 % 32 = 4 -> rows 8 apart alias a bank pair (2-way = free)
__global__ __launch_bounds__(256) void agg_kernel(
    const float* __restrict__ pts,
    const float* __restrict__ feat,
    const float* __restrict__ w_geom,
    const float* __restrict__ g1, const float* __restrict__ b1,
    const float* __restrict__ m1, const float* __restrict__ v1,
    const float* __restrict__ w_sem,
    const float* __restrict__ g2, const float* __restrict__ b2,
    const float* __restrict__ m2, const float* __restrict__ v2,
    const float* __restrict__ w_fuse,
    const float* __restrict__ g3, const float* __restrict__ b3,
    const float* __restrict__ m3, const float* __restrict__ v3,
    const int* __restrict__ knn_idx,
    float* __restrict__ outp) {

    __shared__ alignas(16) unsigned short s_wsemB[8192];    // 16 KB
    __shared__ alignas(16) unsigned short s_wfuseB[8192];   // 16 KB
    __shared__ float s_wg[6][64];
    __shared__ float s_s1[64], s_b1[64], s_s2[64], s_b2[64], s_s3[64], s_b3[64];
    __shared__ alignas(16) float s_mid[4][16][MIDW];        // 17 KB (half-width, reused)
    __shared__ float s_gd[4][16][4];

    const int tid = threadIdx.x;
    const int w = tid >> 6, lane = tid & 63;
    const int r = lane & 15, qd = lane >> 4;

    for (int e = tid; e < 1024; e += 256) {          // e = (kc*4+n0)*64 + ln
        const int ln = e & 63;
        const int o = ((e >> 6) & 3) * 16 + (ln & 15);
        const int c = (e >> 8) * 32 + (ln >> 4) * 8;
        unsigned short ts[8], tf[8];
#pragma unroll
        for (int j = 0; j < 8; ++j) {
            ts[j] = f2bf(w_sem [o * 128 + c + j]);
            tf[j] = f2bf(w_fuse[o * 128 + c + j]);
        }
        *(uint4*)&s_wsemB [e * 8] = *(uint4*)ts;
        *(uint4*)&s_wfuseB[e * 8] = *(uint4*)tf;
    }
    for (int e = tid; e < 384; e += 256) {
        const int c = e >> 6, o = e & 63;
        s_wg[c][o] = w_geom[o * 6 + c];
    }
    if (tid < 64) {
        float s;
        s = g1[tid] / sqrtf(v1[tid] + 1e-5f);
        s_s1[tid] = s; s_b1[tid] = b1[tid] - m1[tid] * s;
        s = g2[tid] / sqrtf(v2[tid] + 1e-5f);
        s_s2[tid] = s; s_b2[tid] = b2[tid] - m2[tid] * s;
        s = g3[tid] / sqrtf(v3[tid] + 1e-5f);
        s_s3[tid] = s; s_b3[tid] = b3[tid] - m3[tid] * s;
    }
    __syncthreads();   // ONLY global barrier: weight staging

    const f32x4 zero = {0.f, 0.f, 0.f, 0.f};

    const int pv0 = blockIdx.x * 16 + w * 4;
    // prefetch point 0's index + center coords
    int nidx_nx;
    float cpx_nx, cpy_nx, cpz_nx;
    {
        const int b = pv0 >> 13, n = pv0 & (NPTS - 1);
        const long pbase = (long)b * NPTS + n;
        nidx_nx = knn_idx[pbase * KNN + r];
        cpx_nx = pts[pbase * 3 + 0];
        cpy_nx = pts[pbase * 3 + 1];
        cpz_nx = pts[pbase * 3 + 2];
    }

#pragma unroll
    for (int i = 0; i < 4; ++i) {
        const int pv = pv0 + i;
        const int b = pv >> 13, n = pv & (NPTS - 1);
        const long pbase = (long)b * NPTS + n;
        const int   nidx_r = nidx_nx;                 // this lane's MFMA-row neighbor
        const float cpx = cpx_nx, cpy = cpy_nx, cpz = cpz_nx;
        const long  nb = (long)b * NPTS + nidx_r;

        if (lane < 16) {                              // r == lane here
            s_gd[w][lane][0] = pts[nb * 3 + 0] - cpx;
            s_gd[w][lane][1] = pts[nb * 3 + 1] - cpy;
            s_gd[w][lane][2] = pts[nb * 3 + 2] - cpz;
        }

        // A-fragments: center features + (neighbor - center), direct global loads
        bf16x8 ah[4], al[4];
        {
            const float* cf = feat + pbase * CH;
            const float* fp = feat + nb * CH;
            float xs[8];
#pragma unroll
            for (int kc = 0; kc < 2; ++kc) {
                const int base = kc * 32 + qd * 8;
                const float4 c0 = *(const float4*)(cf + base);
                const float4 c1 = *(const float4*)(cf + base + 4);
                const float4 v0 = *(const float4*)(fp + base);
                const float4 v1 = *(const float4*)(fp + base + 4);
                xs[0] = c0.x; xs[1] = c0.y; xs[2] = c0.z; xs[3] = c0.w;
                xs[4] = c1.x; xs[5] = c1.y; xs[6] = c1.z; xs[7] = c1.w;
                split8(xs, ah[kc], al[kc]);
                xs[0] = v0.x - c0.x; xs[1] = v0.y - c0.y;
                xs[2] = v0.z - c0.z; xs[3] = v0.w - c0.w;
                xs[4] = v1.x - c1.x; xs[5] = v1.y - c1.y;
                xs[6] = v1.z - c1.z; xs[7] = v1.w - c1.w;
                split8(xs, ah[2 + kc], al[2 + kc]);
            }
        }
        f32x4 acc[4] = {zero, zero, zero, zero};
#pragma unroll
        for (int kc = 0; kc < 4; ++kc) {
#pragma unroll
            for (int n0 = 0; n0 < 4; ++n0) {
                const bf16x8 bw = *(const bf16x8*)&s_wsemB[((kc * 4 + n0) * 64 + lane) * 8];
                acc[n0] = __builtin_amdgcn_mfma_f32_16x16x32_bf16(ah[kc], bw, acc[n0], 0, 0, 0);
                acc[n0] = __builtin_amdgcn_mfma_f32_16x16x32_bf16(al[kc], bw, acc[n0], 0, 0, 0);
            }
        }
        // write sem-mid (channels 64..127 of fuse input) into cols 0..63 of half-buffer
#pragma unroll
        for (int n0 = 0; n0 < 4; ++n0) {
            const int nn = n0 * 16 + r;
            const float sv = s_s2[nn], bv = s_b2[nn];
#pragma unroll
            for (int reg = 0; reg < 4; ++reg) {
                s_mid[w][qd * 4 + reg][nn] = fmaxf(fmaf(acc[n0][reg], sv, bv), 0.f);
            }
        }

        // prefetch next point's idx + center coords (overlaps work below)
        if (i < 3) {
            const int pvn = pv + 1;
            const int bn = pvn >> 13, nn2 = pvn & (NPTS - 1);
            const long pbn = (long)bn * NPTS + nn2;
            nidx_nx = knn_idx[pbn * KNN + r];
            cpx_nx = pts[pbn * 3 + 0];
            cpy_nx = pts[pbn * 3 + 1];
            cpz_nx = pts[pbn * 3 + 2];
        }

        wave_fence();                                 // F1: sem-mid + s_gd visible

        // fuse A-fragments kc=2,3 (sem channels) from half-buffer
        bf16x8 fh[4], fl[4];
        {
            float xs[8];
#pragma unroll
            for (int kc = 0; kc < 2; ++kc) {
                const float* mp = &s_mid[w][r][kc * 32 + qd * 8];
#pragma unroll
                for (int j = 0; j < 8; ++j) xs[j] = mp[j];
                split8(xs, fh[2 + kc], fl[2 + kc]);
            }
        }
        wave_fence();                                 // F2: WAR before geom overwrite

        {
            const int o = lane;
            float cg = cpx * s_wg[0][o];
            cg = fmaf(cpy, s_wg[1][o], cg);
            cg = fmaf(cpz, s_wg[2][o], cg);
            const float s1o = s_s1[o], b1o = s_b1[o];
#pragma unroll
            for (int r2 = 0; r2 < 16; ++r2) {
                float g = cg;
                g = fmaf(s_gd[w][r2][0], s_wg[3][o], g);
                g = fmaf(s_gd[w][r2][1], s_wg[4][o], g);
                g = fmaf(s_gd[w][r2][2], s_wg[5][o], g);
                s_mid[w][r2][o] = fmaxf(fmaf(g, s1o, b1o), 0.f);
            }
        }
        wave_fence();                                 // F3: geom-mid visible

        // fuse A-fragments kc=0,1 (geom channels)
        {
            float xs[8];
#pragma unroll
            for (int kc = 0; kc < 2; ++kc) {
                const float* mp = &s_mid[w][r][kc * 32 + qd * 8];
#pragma unroll
                for (int j = 0; j < 8; ++j) xs[j] = mp[j];
                split8(xs, fh[kc], fl[kc]);
            }
        }

        f32x4 acc2[4] = {zero, zero, zero, zero};
#pragma unroll
        for (int kc = 0; kc < 4; ++kc) {              // accumulation order kc 0..3 unchanged
#pragma unroll
            for (int n0 = 0; n0 < 4; ++n0) {
                const bf16x8 bw = *(const bf16x8*)&s_wfuseB[((kc * 4 + n0) * 64 + lane) * 8];
                acc2[n0] = __builtin_amdgcn_mfma_f32_16x16x32_bf16(fh[kc], bw, acc2[n0], 0, 0, 0);
                acc2[n0] = __builtin_amdgcn_mfma_f32_16x16x32_bf16(fl[kc], bw, acc2[n0], 0, 0, 0);
            }
        }
        // per-n0 reg-max, then cross-qd max via shfl_xor (associative -> bit-exact)
        float red[4];
#pragma unroll
        for (int n0 = 0; n0 < 4; ++n0) {
            const int nn = n0 * 16 + r;
            const float sv = s_s3[nn], bv = s_b3[nn];
            float mx = 0.f;   // relu outputs >= 0
#pragma unroll
            for (int reg = 0; reg < 4; ++reg)
                mx = fmaxf(mx, fmaxf(fmaf(acc2[n0][reg], sv, bv), 0.f));
            mx = fmaxf(mx, __shfl_xor(mx, 16));
            mx = fmaxf(mx, __shfl_xor(mx, 32));
            red[n0] = mx;
        }
        {
            float rv = red[0];
            rv = (qd == 1) ? red[1] : rv;
            rv = (qd == 2) ? red[2] : rv;
            rv = (qd == 3) ? red[3] : rv;
            outp[pbase * CH + lane] = rv;             // channel = qd*16 + r = lane
        }
        wave_fence();                                 // F4: WAR before next iter reuse
    }
}

extern "C" void kernel_launch(void* const* d_in, const int* in_sizes, int n_in,
                              void* d_out, int out_size, void* d_ws, size_t ws_size,
                              hipStream_t stream) {
    (void)in_sizes; (void)n_in; (void)out_size; (void)ws_size;
    const float* pts    = (const float*)d_in[0];
    const float* feat   = (const float*)d_in[1];
    const float* w_geom = (const float*)d_in[2];
    const float* g1     = (const float*)d_in[3];
    const float* b1     = (const float*)d_in[4];
    const float* m1     = (const float*)d_in[5];
    const float* v1     = (const float*)d_in[6];
    const float* w_sem  = (const float*)d_in[7];
    const float* g2     = (const float*)d_in[8];
    const float* b2     = (const float*)d_in[9];
    const float* m2     = (const float*)d_in[10];
    const float* v2     = (const float*)d_in[11];
    const float* w_fuse = (const float*)d_in[12];
    const float* g3     = (const float*)d_in[13];
    const float* b3     = (const float*)d_in[14];
    const float* m3     = (const float*)d_in[15];
    const float* v3     = (const float*)d_in[16];

    int*    idx_final = (int*)d_ws;                             // 2 MB @ 0
    uint4*  bfrag     = (uint4*)((char*)d_ws + (2ull << 20));   // 1 MB @ 2MB
    float4* pts4      = (float4*)((char*)d_ws + (4ull << 20));  // 512 KB @ 4MB

    pack_kernel<<<dim3(NB * NPTS / 256), dim3(256), 0, stream>>>(pts, pts4, bfrag);
    knn_mfma_kernel<<<dim3(NB * NPTS / 32), dim3(256), 0, stream>>>(pts4, bfrag, idx_final);

    agg_kernel<<<dim3(2048), dim3(256), 0, stream>>>(
        pts, feat, w_geom, g1, b1, m1, v1, w_sem, g2, b2, m2, v2,
        w_fuse, g3, b3, m3, v3, idx_final, (float*)d_out);
}

// Round 9
// 244.606 us; speedup vs baseline: 1.0717x; 1.0158x over previous
//
#include <hip/hip_runtime.h>

#define NPTS 8192
#define NB 4
#define CH 64
#define KNN 16
#define CAP2 128          // survivors per query (expected ~20-40; passed rounds at 128)
#define SLACK 4e-3f       // > 2*eps of bf16 hi/lo MFMA distance approx (eps ~ 5e-4)
#define MNVP 129          // s_minv pad: 129 % 32 = 1 -> conflict-free column reads

using bf16x8 = __attribute__((ext_vector_type(8))) __bf16;
using us8    = __attribute__((ext_vector_type(8))) unsigned short;
using f32x4  = __attribute__((ext_vector_type(4))) float;
using f32x16 = __attribute__((ext_vector_type(16))) float;

__device__ __forceinline__ float bf2f(unsigned short u) {
    return __uint_as_float(((unsigned)u) << 16);
}
__device__ __forceinline__ unsigned short f2bf(float f) {
    unsigned u = __float_as_uint(f);
    u += 0x7fffu + ((u >> 16) & 1u);
    return (unsigned short)(u >> 16);
}

// split 8 f32 into hi/lo bf16: x = hi + lo (native casts -> v_cvt_pk_bf16_f32, RNE)
__device__ __forceinline__ void split8(const float* x, bf16x8& hi, bf16x8& lo) {
#pragma unroll
    for (int j = 0; j < 8; ++j) {
        const __bf16 h = (__bf16)x[j];
        hi[j] = h;
        lo[j] = (__bf16)(x[j] - (float)h);
    }
}

// in-wave LDS fence: order prior LDS writes before subsequent reads, no cross-wave stall
__device__ __forceinline__ void wave_fence() {
    asm volatile("s_waitcnt lgkmcnt(0)" ::: "memory");
    __builtin_amdgcn_wave_barrier();
}

// lexicographic (d,i) compare: true if (dB,iB) < (dA,iA)
__device__ __forceinline__ bool lex_lt(float dB, int iB, float dA, int iA) {
    return (dB < dA) || ((dB == dA) && (iB < iA));
}

// ---------------- Kernel 0: pack {x,y,z,sq} + 32x32x16 MFMA B-fragments --------------
// (frozen, passed rounds 3/5/6/7/8)
__global__ __launch_bounds__(256) void pack_kernel(const float* __restrict__ pts,
                                                   float4* __restrict__ pts4,
                                                   uint4* __restrict__ bfrag) {
    const int i = blockIdx.x * 256 + threadIdx.x;   // 0..32767
    const float x = pts[i * 3 + 0];
    const float y = pts[i * 3 + 1];
    const float z = pts[i * 3 + 2];
    const float sq = (x * x + y * y) + z * z;       // reference-path formula
    pts4[i] = make_float4(x, y, z, sq);

    const float sx = -2.f * x, sy = -2.f * y, sz = -2.f * z;
    const unsigned short shx = f2bf(sx), shy = f2bf(sy), shz = f2bf(sz);
    const unsigned short slx = f2bf(sx - bf2f(shx));
    const unsigned short sly = f2bf(sy - bf2f(shy));
    const unsigned short slz = f2bf(sz - bf2f(shz));
    const unsigned short sqh = f2bf(sq), sql = f2bf(sq - bf2f(sqh));

    const int b = i >> 13, n = i & (NPTS - 1);
    const int tile = n >> 5, col = n & 31;
    uint4* base = bfrag + ((size_t)(b * 256 + tile)) * 64;

    unsigned short g0[8], g1[8];
    g0[0] = shx; g0[1] = shy; g0[2] = shz; g0[3] = slx;
    g0[4] = sly; g0[5] = slz; g0[6] = shx; g0[7] = shy;   // k0..7
    g1[0] = shz; g1[1] = slx; g1[2] = sly; g1[3] = slz;
    g1[4] = sqh; g1[5] = sql; g1[6] = 0;   g1[7] = 0;     // k8..15
    base[col]      = *(const uint4*)g0;
    base[32 + col] = *(const uint4*)g1;
}

// A-fragment for one query point, k-half kh = lane>>5 (proven k-plan)
__device__ __forceinline__ bf16x8 make_afrag(const float4 qp, const int kh) {
    const unsigned short hx = f2bf(qp.x), hy = f2bf(qp.y), hz = f2bf(qp.z);
    const unsigned short lx = f2bf(qp.x - bf2f(hx));
    const unsigned short ly = f2bf(qp.y - bf2f(hy));
    const unsigned short lz = f2bf(qp.z - bf2f(hz));
    us8 u;
#pragma unroll
    for (int j = 0; j < 8; ++j) u[j] = 0;
    if (kh == 0) {
        u[0] = hx; u[1] = hy; u[2] = hz; u[3] = hx;
        u[4] = hy; u[5] = hz; u[6] = lx; u[7] = ly;       // k0..7
    } else {
        u[0] = lz; u[1] = lx; u[2] = ly; u[3] = lz;
        u[4] = 0x3f80u; u[5] = 0x3f80u;                   // 1.0 * sq_hi/lo, k8..15
    }
    return __builtin_bit_cast(bf16x8, u);
}

// ---------------- Kernel 1: MFMA KNN — depth-1 pipelined passes ----------------------
// vs round-8 (93.6 µs): (a) both passes reduce/admit the PREVIOUS tile's MFMA result
// (a_prev, init +INF -> dummy step harmless) so the VALU never waits on the
// just-issued MFMA; (b) U-select inner loop fully unrolled (64 independent broadcast
// ds_reads in flight); (c) epilogue software-pipelined: next query's s_cnt/s_surv/
// gather chain issues before this query's rank loop. Selection semantics identical.
__global__ __launch_bounds__(256, 4) void knn_mfma_kernel(const float4* __restrict__ pts4,
                                                          const uint4* __restrict__ bfrag,
                                                          int* __restrict__ idx_out) {
    __shared__ alignas(16) char s_union[32 * MNVP * 4];   // 16,512 B
    float (*s_minv)[MNVP] = (float(*)[MNVP])s_union;      // [32][129], dead after B3
    int   (*s_surv)[CAP2] = (int(*)[CAP2])s_union;        // [32][128], written after B3
    __shared__ float s_U[32];
    __shared__ int   s_cnt[32];
    __shared__ float s_rd[4][CAP2];
    __shared__ int   s_ri[4][CAP2];

    const int tid  = threadIdx.x;
    const int w    = tid >> 6, lane = tid & 63;
    const int col  = lane & 31, hi = lane >> 5;
    const int qbase = blockIdx.x * 32;               // global query id (= b*8192 + n0)
    const int b = qbase >> 13, n0 = qbase & (NPTS - 1);
    const float4* pb = pts4 + (size_t)b * NPTS;

    // A-fragment: rows = queries n0..n0+31
    const bf16x8 af = make_afrag(pb[n0 + col], hi);

    const int wtile = w * 64;
    const uint4* bpb = bfrag + ((size_t)b * 256) * 64;    // batch base
    const f32x16 zero16 = {0.f, 0.f, 0.f, 0.f, 0.f, 0.f, 0.f, 0.f,
                           0.f, 0.f, 0.f, 0.f, 0.f, 0.f, 0.f, 0.f};
    const f32x16 inf16 = {3.4e38f, 3.4e38f, 3.4e38f, 3.4e38f, 3.4e38f, 3.4e38f, 3.4e38f, 3.4e38f,
                          3.4e38f, 3.4e38f, 3.4e38f, 3.4e38f, 3.4e38f, 3.4e38f, 3.4e38f, 3.4e38f};

    // ---- Pass A: stream minima of e = |c|^2 - 2 q.c, 8-deep load ring + 1-deep MFMA pipe
    float m0[16];
#pragma unroll
    for (int r = 0; r < 16; ++r) m0[r] = 3.4e38f;

    uint4 pf0 = bpb[(wtile + 0) * 64 + lane], pf1 = bpb[(wtile + 1) * 64 + lane];
    uint4 pf2 = bpb[(wtile + 2) * 64 + lane], pf3 = bpb[(wtile + 3) * 64 + lane];
    uint4 pf4 = bpb[(wtile + 4) * 64 + lane], pf5 = bpb[(wtile + 5) * 64 + lane];
    uint4 pf6 = bpb[(wtile + 6) * 64 + lane], pf7 = bpb[(wtile + 7) * 64 + lane];

    f32x16 a_prev = inf16;   // dummy first step: fmin(x, INF) = x

#define STEP_A(PF, KOFF)                                                              \
    {                                                                                 \
        const bf16x8 bw = __builtin_bit_cast(bf16x8, PF);                             \
        PF = bpb[min(wtile + tb + 8 + KOFF, 255) * 64 + lane];                        \
        const f32x16 a_cur = __builtin_amdgcn_mfma_f32_32x32x16_bf16(af, bw, zero16, 0, 0, 0); \
        _Pragma("unroll")                                                             \
        for (int r = 0; r < 16; ++r) m0[r] = fminf(m0[r], a_prev[r]);                 \
        a_prev = a_cur;                                                               \
    }

    for (int tt = 0; tt < 8; ++tt) {
        const int tb = tt * 8;
        STEP_A(pf0, 0)
        STEP_A(pf1, 1)
        STEP_A(pf2, 2)
        STEP_A(pf3, 3)
        STEP_A(pf4, 4)
        STEP_A(pf5, 5)
        STEP_A(pf6, 6)
        STEP_A(pf7, 7)
    }
#undef STEP_A
#pragma unroll
    for (int r = 0; r < 16; ++r) m0[r] = fminf(m0[r], a_prev[r]);   // tile 63

    // C/D layout (verified): col=lane&31 (cand-class), row=(r&3)+8*(r>>2)+4*hi (query).
#pragma unroll
    for (int r = 0; r < 16; ++r) {
        const int q0 = (r & 3) + 8 * (r >> 2) + 4 * hi;
        s_minv[q0][w * 32 + col] = m0[r];
    }
    if (tid < 32) s_cnt[tid] = 0;
    __syncthreads();                                  // B1 (all 128 streams written)

    // ---- combine 128 -> 64 streams (pairwise min over disjoint candidate sets) ----
#pragma unroll
    for (int e0 = 0; e0 < 8; ++e0) {
        const int e = e0 * 256 + tid;
        const int q = e >> 6, j = e & 63;
        s_minv[q][j] = fminf(s_minv[q][j], s_minv[q][64 + j]);
    }
    __syncthreads();                                  // B2

    // ---- U select: rank-15 (16th smallest) of 64 stream minima per query ----
    for (int qi = 0; qi < 8; ++qi) {
        const int q = w * 8 + qi;
        const float v = s_minv[q][lane];
        int rk = 0;
#pragma unroll
        for (int j = 0; j < 64; ++j) {
            const float vv = s_minv[q][j];
            rk += ((vv < v) || (vv == v && j < lane)) ? 1 : 0;
        }
        if (rk == 15) s_U[q] = v;                     // exactly one (value,stream) wins
    }
    __syncthreads();                                  // B3 (last s_minv read; s_surv writable)

    // ---- Pass B: gated admission (predicated LDS atomics), 1-deep MFMA pipe ----
    float U0[16];
#pragma unroll
    for (int r = 0; r < 16; ++r) {
        const int q0 = (r & 3) + 8 * (r >> 2) + 4 * hi;
        U0[r] = s_U[q0] + SLACK;
    }

    pf0 = bpb[(wtile + 0) * 64 + lane]; pf1 = bpb[(wtile + 1) * 64 + lane];
    pf2 = bpb[(wtile + 2) * 64 + lane]; pf3 = bpb[(wtile + 3) * 64 + lane];
    pf4 = bpb[(wtile + 4) * 64 + lane]; pf5 = bpb[(wtile + 5) * 64 + lane];
    pf6 = bpb[(wtile + 6) * 64 + lane]; pf7 = bpb[(wtile + 7) * 64 + lane];

    a_prev = inf16;   // dummy first step: INF <= U never true

#define STEP_B(PF, KOFF)                                                              \
    {                                                                                 \
        const bf16x8 bw = __builtin_bit_cast(bf16x8, PF);                             \
        PF = bpb[min(wtile + tb + 8 + KOFF, 255) * 64 + lane];                        \
        const f32x16 a_cur = __builtin_amdgcn_mfma_f32_32x32x16_bf16(af, bw, zero16, 0, 0, 0); \
        const int candp = (wtile + tb + KOFF - 1) * 32 + col;   /* PREVIOUS tile */   \
        _Pragma("unroll")                                                             \
        for (int r = 0; r < 16; ++r) {                                                \
            if (a_prev[r] <= U0[r]) {                                                 \
                const int q0 = (r & 3) + 8 * (r >> 2) + 4 * hi;                       \
                const int pos = atomicAdd(&s_cnt[q0], 1);                             \
                if (pos < CAP2) s_surv[q0][pos] = candp;                              \
            }                                                                         \
        }                                                                             \
        a_prev = a_cur;                                                               \
    }

    for (int tt = 0; tt < 8; ++tt) {
        const int tb = tt * 8;
        STEP_B(pf0, 0)
        STEP_B(pf1, 1)
        STEP_B(pf2, 2)
        STEP_B(pf3, 3)
        STEP_B(pf4, 4)
        STEP_B(pf5, 5)
        STEP_B(pf6, 6)
        STEP_B(pf7, 7)
    }
#undef STEP_B
    {   // admit tile 63 (held in a_prev)
        const int candp = (wtile + 63) * 32 + col;
#pragma unroll
        for (int r = 0; r < 16; ++r) {
            if (a_prev[r] <= U0[r]) {
                const int q0 = (r & 3) + 8 * (r >> 2) + 4 * hi;
                const int pos = atomicAdd(&s_cnt[q0], 1);
                if (pos < CAP2) s_surv[q0][pos] = candp;
            }
        }
    }
    __syncthreads();                                  // B4

    // ---- Epilogue: exact distances + lex rank, software-pipelined per query ----
    int    n_nx, i1_nx = -1, i2_nx = -1;
    float4 qp_nx, v1_nx, v2_nx;
    {
        const int q = w * 8;
        n_nx = min(s_cnt[q], CAP2);
        qp_nx = pb[n0 + q];
        if (lane < n_nx)      { i1_nx = s_surv[q][lane];      v1_nx = pb[i1_nx]; }
        if (64 + lane < n_nx) { i2_nx = s_surv[q][64 + lane]; v2_nx = pb[i2_nx]; }
    }
    for (int qi = 0; qi < 8; ++qi) {
        const int q = w * 8 + qi;
        const int n = n_nx;
        const float4 qp = qp_nx;
        const int i1 = i1_nx, i2 = i2_nx;
        float d1 = 3.4e38f, d2 = 3.4e38f;
        if (lane < n) {
            const float4 v = v1_nx;
            float dot = qp.x * v.x;
            dot = fmaf(qp.y, v.y, dot);
            dot = fmaf(qp.z, v.z, dot);
            d1 = fmaf(dot, -2.0f, qp.w + v.w);        // identical rounding to reference path
        }
        if (64 + lane < n) {
            const float4 v = v2_nx;
            float dot = qp.x * v.x;
            dot = fmaf(qp.y, v.y, dot);
            dot = fmaf(qp.z, v.z, dot);
            d2 = fmaf(dot, -2.0f, qp.w + v.w);
        }
        s_rd[w][lane] = d1;      s_ri[w][lane] = i1;
        s_rd[w][64 + lane] = d2; s_ri[w][64 + lane] = i2;
        wave_fence();                                 // in-wave LDS producer/consumer
        if (qi < 7) {                                 // issue next query's load chain now;
            const int qn = q + 1;                     // overlaps the rank loop below
            n_nx = min(s_cnt[qn], CAP2);
            qp_nx = pb[n0 + qn];
            i1_nx = -1; i2_nx = -1;
            if (lane < n_nx)      { i1_nx = s_surv[qn][lane];      v1_nx = pb[i1_nx]; }
            if (64 + lane < n_nx) { i2_nx = s_surv[qn][64 + lane]; v2_nx = pb[i2_nx]; }
        }
        int r1 = 0, r2 = 0;
        int k = 0;
        for (; k + 7 < n; k += 8) {
#pragma unroll
            for (int u = 0; u < 8; ++u) {
                const float dk = s_rd[w][k + u];
                const int   ik = s_ri[w][k + u];
                r1 += lex_lt(dk, ik, d1, i1) ? 1 : 0;
                r2 += lex_lt(dk, ik, d2, i2) ? 1 : 0;
            }
        }
        for (; k < n; ++k) {
            const float dk = s_rd[w][k];
            const int   ik = s_ri[w][k];
            r1 += lex_lt(dk, ik, d1, i1) ? 1 : 0;
            r2 += lex_lt(dk, ik, d2, i2) ? 1 : 0;
        }
        if (lane < n && r1 < KNN)      idx_out[(size_t)(qbase + q) * KNN + r1] = i1;
        if (64 + lane < n && r2 < KNN) idx_out[(size_t)(qbase + q) * KNN + r2] = i2;
        wave_fence();                                 // scratch WAR across queries (in-wave)
    }
}

// ---------------- Kernel 2: MFMA agg — LDS diet, 3 blocks/CU (frozen, passed r8) -----
#define MIDW 68    // 68 % 32 = 4 -> rows 8 apart alias a bank pair (2-way = free)
__global__ __launch_bounds__(256) void agg_kernel(
    const float* __restrict__ pts,
    const float* __restrict__ feat,
    const float* __restrict__ w_geom,
    const float* __restrict__ g1, const float* __restrict__ b1,
    const float* __restrict__ m1, const float* __restrict__ v1,
    const float* __restrict__ w_sem,
    const float* __restrict__ g2, const float* __restrict__ b2,
    const float* __restrict__ m2, const float* __restrict__ v2,
    const float* __restrict__ w_fuse,
    const float* __restrict__ g3, const float* __restrict__ b3,
    const float* __restrict__ m3, const float* __restrict__ v3,
    const int* __restrict__ knn_idx,
    float* __restrict__ outp) {

    __shared__ alignas(16) unsigned short s_wsemB[8192];    // 16 KB
    __shared__ alignas(16) unsigned short s_wfuseB[8192];   // 16 KB
    __shared__ float s_wg[6][64];
    __shared__ float s_s1[64], s_b1[64], s_s2[64], s_b2[64], s_s3[64], s_b3[64];
    __shared__ alignas(16) float s_mid[4][16][MIDW];        // 17 KB (half-width, reused)
    __shared__ float s_gd[4][16][4];

    const int tid = threadIdx.x;
    const int w = tid >> 6, lane = tid & 63;
    const int r = lane & 15, qd = lane >> 4;

    for (int e = tid; e < 1024; e += 256) {          // e = (kc*4+n0)*64 + ln
        const int ln = e & 63;
        const int o = ((e >> 6) & 3) * 16 + (ln & 15);
        const int c = (e >> 8) * 32 + (ln >> 4) * 8;
        unsigned short ts[8], tf[8];
#pragma unroll
        for (int j = 0; j < 8; ++j) {
            ts[j] = f2bf(w_sem [o * 128 + c + j]);
            tf[j] = f2bf(w_fuse[o * 128 + c + j]);
        }
        *(uint4*)&s_wsemB [e * 8] = *(uint4*)ts;
        *(uint4*)&s_wfuseB[e * 8] = *(uint4*)tf;
    }
    for (int e = tid; e < 384; e += 256) {
        const int c = e >> 6, o = e & 63;
        s_wg[c][o] = w_geom[o * 6 + c];
    }
    if (tid < 64) {
        float s;
        s = g1[tid] / sqrtf(v1[tid] + 1e-5f);
        s_s1[tid] = s; s_b1[tid] = b1[tid] - m1[tid] * s;
        s = g2[tid] / sqrtf(v2[tid] + 1e-5f);
        s_s2[tid] = s; s_b2[tid] = b2[tid] - m2[tid] * s;
        s = g3[tid] / sqrtf(v3[tid] + 1e-5f);
        s_s3[tid] = s; s_b3[tid] = b3[tid] - m3[tid] * s;
    }
    __syncthreads();   // ONLY global barrier: weight staging

    const f32x4 zero = {0.f, 0.f, 0.f, 0.f};

    const int pv0 = blockIdx.x * 16 + w * 4;
    // prefetch point 0's index + center coords
    int nidx_nx;
    float cpx_nx, cpy_nx, cpz_nx;
    {
        const int b = pv0 >> 13, n = pv0 & (NPTS - 1);
        const long pbase = (long)b * NPTS + n;
        nidx_nx = knn_idx[pbase * KNN + r];
        cpx_nx = pts[pbase * 3 + 0];
        cpy_nx = pts[pbase * 3 + 1];
        cpz_nx = pts[pbase * 3 + 2];
    }

#pragma unroll
    for (int i = 0; i < 4; ++i) {
        const int pv = pv0 + i;
        const int b = pv >> 13, n = pv & (NPTS - 1);
        const long pbase = (long)b * NPTS + n;
        const int   nidx_r = nidx_nx;                 // this lane's MFMA-row neighbor
        const float cpx = cpx_nx, cpy = cpy_nx, cpz = cpz_nx;
        const long  nb = (long)b * NPTS + nidx_r;

        if (lane < 16) {                              // r == lane here
            s_gd[w][lane][0] = pts[nb * 3 + 0] - cpx;
            s_gd[w][lane][1] = pts[nb * 3 + 1] - cpy;
            s_gd[w][lane][2] = pts[nb * 3 + 2] - cpz;
        }

        // A-fragments: center features + (neighbor - center), direct global loads
        bf16x8 ah[4], al[4];
        {
            const float* cf = feat + pbase * CH;
            const float* fp = feat + nb * CH;
            float xs[8];
#pragma unroll
            for (int kc = 0; kc < 2; ++kc) {
                const int base = kc * 32 + qd * 8;
                const float4 c0 = *(const float4*)(cf + base);
                const float4 c1 = *(const float4*)(cf + base + 4);
                const float4 v0 = *(const float4*)(fp + base);
                const float4 v1 = *(const float4*)(fp + base + 4);
                xs[0] = c0.x; xs[1] = c0.y; xs[2] = c0.z; xs[3] = c0.w;
                xs[4] = c1.x; xs[5] = c1.y; xs[6] = c1.z; xs[7] = c1.w;
                split8(xs, ah[kc], al[kc]);
                xs[0] = v0.x - c0.x; xs[1] = v0.y - c0.y;
                xs[2] = v0.z - c0.z; xs[3] = v0.w - c0.w;
                xs[4] = v1.x - c1.x; xs[5] = v1.y - c1.y;
                xs[6] = v1.z - c1.z; xs[7] = v1.w - c1.w;
                split8(xs, ah[2 + kc], al[2 + kc]);
            }
        }
        f32x4 acc[4] = {zero, zero, zero, zero};
#pragma unroll
        for (int kc = 0; kc < 4; ++kc) {
#pragma unroll
            for (int n0 = 0; n0 < 4; ++n0) {
                const bf16x8 bw = *(const bf16x8*)&s_wsemB[((kc * 4 + n0) * 64 + lane) * 8];
                acc[n0] = __builtin_amdgcn_mfma_f32_16x16x32_bf16(ah[kc], bw, acc[n0], 0, 0, 0);
                acc[n0] = __builtin_amdgcn_mfma_f32_16x16x32_bf16(al[kc], bw, acc[n0], 0, 0, 0);
            }
        }
        // write sem-mid (channels 64..127 of fuse input) into cols 0..63 of half-buffer
#pragma unroll
        for (int n0 = 0; n0 < 4; ++n0) {
            const int nn = n0 * 16 + r;
            const float sv = s_s2[nn], bv = s_b2[nn];
#pragma unroll
            for (int reg = 0; reg < 4; ++reg) {
                s_mid[w][qd * 4 + reg][nn] = fmaxf(fmaf(acc[n0][reg], sv, bv), 0.f);
            }
        }

        // prefetch next point's idx + center coords (overlaps work below)
        if (i < 3) {
            const int pvn = pv + 1;
            const int bn = pvn >> 13, nn2 = pvn & (NPTS - 1);
            const long pbn = (long)bn * NPTS + nn2;
            nidx_nx = knn_idx[pbn * KNN + r];
            cpx_nx = pts[pbn * 3 + 0];
            cpy_nx = pts[pbn * 3 + 1];
            cpz_nx = pts[pbn * 3 + 2];
        }

        wave_fence();                                 // F1: sem-mid + s_gd visible

        // fuse A-fragments kc=2,3 (sem channels) from half-buffer
        bf16x8 fh[4], fl[4];
        {
            float xs[8];
#pragma unroll
            for (int kc = 0; kc < 2; ++kc) {
                const float* mp = &s_mid[w][r][kc * 32 + qd * 8];
#pragma unroll
                for (int j = 0; j < 8; ++j) xs[j] = mp[j];
                split8(xs, fh[2 + kc], fl[2 + kc]);
            }
        }
        wave_fence();                                 // F2: WAR before geom overwrite

        {
            const int o = lane;
            float cg = cpx * s_wg[0][o];
            cg = fmaf(cpy, s_wg[1][o], cg);
            cg = fmaf(cpz, s_wg[2][o], cg);
            const float s1o = s_s1[o], b1o = s_b1[o];
#pragma unroll
            for (int r2 = 0; r2 < 16; ++r2) {
                float g = cg;
                g = fmaf(s_gd[w][r2][0], s_wg[3][o], g);
                g = fmaf(s_gd[w][r2][1], s_wg[4][o], g);
                g = fmaf(s_gd[w][r2][2], s_wg[5][o], g);
                s_mid[w][r2][o] = fmaxf(fmaf(g, s1o, b1o), 0.f);
            }
        }
        wave_fence();                                 // F3: geom-mid visible

        // fuse A-fragments kc=0,1 (geom channels)
        {
            float xs[8];
#pragma unroll
            for (int kc = 0; kc < 2; ++kc) {
                const float* mp = &s_mid[w][r][kc * 32 + qd * 8];
#pragma unroll
                for (int j = 0; j < 8; ++j) xs[j] = mp[j];
                split8(xs, fh[kc], fl[kc]);
            }
        }

        f32x4 acc2[4] = {zero, zero, zero, zero};
#pragma unroll
        for (int kc = 0; kc < 4; ++kc) {              // accumulation order kc 0..3 unchanged
#pragma unroll
            for (int n0 = 0; n0 < 4; ++n0) {
                const bf16x8 bw = *(const bf16x8*)&s_wfuseB[((kc * 4 + n0) * 64 + lane) * 8];
                acc2[n0] = __builtin_amdgcn_mfma_f32_16x16x32_bf16(fh[kc], bw, acc2[n0], 0, 0, 0);
                acc2[n0] = __builtin_amdgcn_mfma_f32_16x16x32_bf16(fl[kc], bw, acc2[n0], 0, 0, 0);
            }
        }
        // per-n0 reg-max, then cross-qd max via shfl_xor (associative -> bit-exact)
        float red[4];
#pragma unroll
        for (int n0 = 0; n0 < 4; ++n0) {
            const int nn = n0 * 16 + r;
            const float sv = s_s3[nn], bv = s_b3[nn];
            float mx = 0.f;   // relu outputs >= 0
#pragma unroll
            for (int reg = 0; reg < 4; ++reg)
                mx = fmaxf(mx, fmaxf(fmaf(acc2[n0][reg], sv, bv), 0.f));
            mx = fmaxf(mx, __shfl_xor(mx, 16));
            mx = fmaxf(mx, __shfl_xor(mx, 32));
            red[n0] = mx;
        }
        {
            float rv = red[0];
            rv = (qd == 1) ? red[1] : rv;
            rv = (qd == 2) ? red[2] : rv;
            rv = (qd == 3) ? red[3] : rv;
            outp[pbase * CH + lane] = rv;             // channel = qd*16 + r = lane
        }
        wave_fence();                                 // F4: WAR before next iter reuse
    }
}

extern "C" void kernel_launch(void* const* d_in, const int* in_sizes, int n_in,
                              void* d_out, int out_size, void* d_ws, size_t ws_size,
                              hipStream_t stream) {
    (void)in_sizes; (void)n_in; (void)out_size; (void)ws_size;
    const float* pts    = (const float*)d_in[0];
    const float* feat   = (const float*)d_in[1];
    const float* w_geom = (const float*)d_in[2];
    const float* g1     = (const float*)d_in[3];
    const float* b1     = (const float*)d_in[4];
    const float* m1     = (const float*)d_in[5];
    const float* v1     = (const float*)d_in[6];
    const float* w_sem  = (const float*)d_in[7];
    const float* g2     = (const float*)d_in[8];
    const float* b2     = (const float*)d_in[9];
    const float* m2     = (const float*)d_in[10];
    const float* v2     = (const float*)d_in[11];
    const float* w_fuse = (const float*)d_in[12];
    const float* g3     = (const float*)d_in[13];
    const float* b3     = (const float*)d_in[14];
    const float* m3     = (const float*)d_in[15];
    const float* v3     = (const float*)d_in[16];

    int*    idx_final = (int*)d_ws;                             // 2 MB @ 0
    uint4*  bfrag     = (uint4*)((char*)d_ws + (2ull << 20));   // 1 MB @ 2MB
    float4* pts4      = (float4*)((char*)d_ws + (4ull << 20));  // 512 KB @ 4MB

    pack_kernel<<<dim3(NB * NPTS / 256), dim3(256), 0, stream>>>(pts, pts4, bfrag);
    knn_mfma_kernel<<<dim3(NB * NPTS / 32), dim3(256), 0, stream>>>(pts4, bfrag, idx_final);

    agg_kernel<<<dim3(2048), dim3(256), 0, stream>>>(
        pts, feat, w_geom, g1, b1, m1, v1, w_sem, g2, b2, m2, v2,
        w_fuse, g3, b3, m3, v3, idx_final, (float*)d_out);
}